// Round 27
// baseline (837.485 us; speedup 1.0000x reference)
//
#include <hip/hip_runtime.h>
#include <hip/hip_bf16.h>
#include <math.h>

// build s27 = r26 + 2-points-per-thread tail (shared s_load weight streams,
// ILP across two gelu chains, zero LDS / no syncthreads in the tail).
#define XYZ 135168   // 64*64*33
#define W 20
#define NMODE 2048   // 16*16*8
#define NREAL 3584   // 16*16*14

__device__ __forceinline__ float s27_erf(float x) {
    float s = (x < 0.f) ? -1.f : 1.f;
    float a = fabsf(x);
    float t = 1.f / fmaf(0.3275911f, a, 1.f);
    float poly = t * fmaf(t, fmaf(t, fmaf(t, fmaf(t, 1.061405429f, -1.453152027f),
                                           1.421413741f), -0.284496736f), 0.254829592f);
    float e = __expf(-a * a);
    return s * (1.f - poly * e);
}
__device__ __forceinline__ float s27_gelu(float v) {
    return 0.5f * v * (1.0f + s27_erf(v * 0.7071067811865476f));
}

__global__ __launch_bounds__(256, 4)
void s27_fc0(const float* __restrict__ xr_in, const float* __restrict__ xi_in,
             const float* __restrict__ fr, const float* __restrict__ fi,
             float* __restrict__ xre, float* __restrict__ xim,
             float* __restrict__ xcRe, float* __restrict__ xcIm) {
    int idx = blockIdx.x * blockDim.x + threadIdx.x;
    if (idx >= 4 * XYZ) return;
    int b = idx / XYZ, p = idx % XYZ;
    int gz = p % 33;
    int gxy = p / 33;
    int gy = gxy & 63;
    int gx = gxy >> 6;
    int kx = (gx < 8) ? gx : ((gx >= 56) ? gx - 48 : -1);
    int ky = (gy < 8) ? gy : ((gy >= 56) ? gy - 48 : -1);
    bool corner = (kx >= 0) && (ky >= 0) && (gz < 8);
    int cidx = corner ? (gz * 256 + kx * 16 + ky) : 0;
    float ar[3], ai[3];
#pragma unroll
    for (int i = 0; i < 3; i++) {
        ar[i] = xr_in[(size_t)(b * 3 + i) * XYZ + p];
        ai[i] = xi_in[(size_t)(b * 3 + i) * XYZ + p];
    }
#pragma unroll
    for (int o = 0; o < W; o++) {
        float rr = 0.f, ii = 0.f;
#pragma unroll
        for (int i = 0; i < 3; i++) {
            float wr = fr[i * W + o], wi = fi[i * W + o];
            rr += ar[i] * wr - ai[i] * wi;
            ii += ar[i] * wi + ai[i] * wr;
        }
        xre[(size_t)(b * W + o) * XYZ + p] = rr;
        xim[(size_t)(b * W + o) * XYZ + p] = ii;
        if (corner) {
            xcRe[(size_t)(b * W + o) * 2048 + cidx] = rr;
            xcIm[(size_t)(b * W + o) * 2048 + cidx] = ii;
        }
    }
}

__global__ __launch_bounds__(256, 4)
void s27_ixy(const float* __restrict__ xcRe, const float* __restrict__ xcIm,
             float* __restrict__ aRe, float* __restrict__ aIm) {
    __shared__ float s0r[256], s0i[256], s1r[256], s1i[256];
    __shared__ float twc[16], tws[16];
    int bc = blockIdx.x >> 3;
    int kz = blockIdx.x & 7;
    int t = threadIdx.x;
    int hi = t >> 4, lo = t & 15;
    if (t < 16) {
        float s, c;
        sincosf((float)t * 0.39269908169872414f, &s, &c);
        twc[t] = c; tws[t] = s;
    }
    {
        size_t g = (size_t)bc * 2048 + (size_t)kz * 256 + t;
        s0r[t] = xcRe[g];
        s0i[t] = xcIm[g];
    }
    __syncthreads();
    {
        int nx = hi, ky = lo;
        float accr = 0.f, acci = 0.f;
        for (int kx = 0; kx < 16; kx++) {
            float vr = s0r[kx * 16 + ky], vi = s0i[kx * 16 + ky];
            int m = (kx * nx) & 15;
            float c = twc[m], s = tws[m];
            accr += vr * c - vi * s;
            acci += vr * s + vi * c;
        }
        s1r[t] = accr * 0.0625f;
        s1i[t] = acci * 0.0625f;
    }
    __syncthreads();
    {
        int nx = hi, ny = lo;
        float accr = 0.f, acci = 0.f;
        for (int ky = 0; ky < 16; ky++) {
            float vr = s1r[nx * 16 + ky], vi = s1i[nx * 16 + ky];
            int m = (ky * ny) & 15;
            float c = twc[m], s = tws[m];
            accr += vr * c - vi * s;
            acci += vr * s + vi * c;
        }
        size_t o = (size_t)bc * 2048 + (size_t)t * 8 + kz;
        aRe[o] = accr * 0.0625f;
        aIm[o] = acci * 0.0625f;
    }
}

__global__ __launch_bounds__(256, 4)
void s27_zchain(const float* __restrict__ aRe, const float* __restrict__ aIm,
                const float* __restrict__ wconv, int l,
                float* __restrict__ tRe, float* __restrict__ tIm) {
    __shared__ float sar[640], sai[640];
    __shared__ float sr1[1120], sr2[1120];
    __shared__ float twc[14], tws[14];
    int b = blockIdx.x >> 6;
    int q0 = (blockIdx.x & 63) * 4;
    int tid = threadIdx.x;
    if (tid < 14) {
        float s, c;
        sincosf((float)tid * 0.4487989505128276f, &s, &c);
        twc[tid] = c; tws[tid] = s;
    }
    for (int t = tid; t < 640; t += 256) {
        int c = t >> 5;
        int dq = (t >> 3) & 3;
        int k = t & 7;
        size_t g = (size_t)(b * 20 + c) * 2048 + (size_t)(q0 + dq) * 8 + k;
        sar[t] = aRe[g];
        sai[t] = aIm[g];
    }
    __syncthreads();
    for (int t = tid; t < 1120; t += 256) {
        int c = t / 56;
        int rem = t % 56;
        int dq = rem / 14, nz = rem % 14;
        int base = c * 32 + dq * 8;
        float acc = sar[base];
        float re7 = sar[base + 7];
        acc += (nz & 1) ? -re7 : re7;
        for (int k = 1; k < 7; k++) {
            int m = (k * nz) % 14;
            acc += 2.f * (sar[base + k] * twc[m] - sai[base + k] * tws[m]);
        }
        sr1[t] = acc * (1.0f / 14.0f);
    }
    __syncthreads();
    {
        const float* wl = wconv + (size_t)l * W * W * NREAL;
        for (int t = tid; t < 1120; t += 256) {
            int o = t / 56;
            int rem = t % 56;
            int dq = rem / 14, nz = rem % 14;
            int p = (q0 + dq) * 14 + nz;
            float acc = 0.f;
#pragma unroll 4
            for (int i = 0; i < W; i++)
                acc += sr1[i * 56 + rem] * wl[(size_t)(i * W + o) * NREAL + p];
            sr2[t] = acc;
        }
    }
    __syncthreads();
    for (int t = tid; t < 640; t += 256) {
        int c = t >> 5;
        int dq = (t >> 3) & 3;
        int k = t & 7;
        int base = c * 56 + dq * 14;
        float accr = 0.f, acci = 0.f;
        for (int n = 0; n < 14; n++) {
            float v = sr2[base + n];
            int m = (k * n) % 14;
            accr += v * twc[m];
            acci -= v * tws[m];
        }
        size_t g = (size_t)(b * 20 + c) * 2048 + (size_t)(q0 + dq) * 8 + k;
        tRe[g] = accr;
        tIm[g] = acci;
    }
}

__global__ __launch_bounds__(256, 4)
void s27_fxy(const float* __restrict__ c1Re, const float* __restrict__ c1Im,
             float* __restrict__ eRe, float* __restrict__ eIm) {
    __shared__ float s0r[256], s0i[256], s1r[256], s1i[256];
    __shared__ float twc[16], tws[16];
    int bc = blockIdx.x >> 3;
    int kz = blockIdx.x & 7;
    int t = threadIdx.x;
    int hi = t >> 4, lo = t & 15;
    if (t < 16) {
        float s, c;
        sincosf((float)t * 0.39269908169872414f, &s, &c);
        twc[t] = c; tws[t] = s;
    }
    {
        size_t o = (size_t)bc * 2048 + (size_t)t * 8 + kz;
        s0r[t] = c1Re[o];
        s0i[t] = c1Im[o];
    }
    __syncthreads();
    {
        int kx = hi, ny = lo;
        float accr = 0.f, acci = 0.f;
        for (int nx = 0; nx < 16; nx++) {
            float vr = s0r[nx * 16 + ny], vi = s0i[nx * 16 + ny];
            int m = (kx * nx) & 15;
            float c = twc[m], s = tws[m];
            accr += vr * c + vi * s;
            acci += vi * c - vr * s;
        }
        s1r[t] = accr;
        s1i[t] = acci;
    }
    __syncthreads();
    {
        int kx = hi, ky = lo;
        float accr = 0.f, acci = 0.f;
        for (int ny = 0; ny < 16; ny++) {
            float vr = s1r[kx * 16 + ny], vi = s1i[kx * 16 + ny];
            int m = (ky * ny) & 15;
            float c = twc[m], s = tws[m];
            accr += vr * c + vi * s;
            acci += vi * c - vr * s;
        }
        size_t o = (size_t)bc * 2048 + (size_t)t * 8 + kz;
        eRe[o] = accr;
        eIm[o] = acci;
    }
}

__global__ __launch_bounds__(256, 4)
void s27_combine(float* __restrict__ xre, float* __restrict__ xim,
                 const float* __restrict__ ere, const float* __restrict__ eim,
                 const float* __restrict__ wpt_r, const float* __restrict__ wpt_i,
                 int l, const float* __restrict__ smooth,
                 float* __restrict__ xcRe, float* __restrict__ xcIm) {
    const float* wr = wpt_r + l * W * W;
    const float* wi = wpt_i + l * W * W;
    int idx = blockIdx.x * blockDim.x + threadIdx.x;
    if (idx >= 4 * XYZ) return;
    int b = idx / XYZ, p = idx % XYZ;
    int gz = p % 33;
    int gxy = p / 33;
    int gy = gxy & 63;
    int gx = gxy >> 6;
    int kx = (gx < 8) ? gx : ((gx >= 56) ? gx - 48 : -1);
    int ky = (gy < 8) ? gy : ((gy >= 56) ? gy - 48 : -1);
    bool corner = (kx >= 0) && (ky >= 0) && (gz < 8);
    int cidx = corner ? (gz * 256 + kx * 16 + ky) : 0;
    float sm = smooth[p];
    float ar[W], ai[W];
#pragma unroll
    for (int i = 0; i < W; i++) {
        ar[i] = xre[(size_t)(b * W + i) * XYZ + p];
        ai[i] = xim[(size_t)(b * W + i) * XYZ + p];
    }
    int ebase = corner ? (b * W * NMODE + (kx * 16 + ky) * 8 + gz) : 0;
    for (int o = 0; o < W; o++) {
        float rr = 0.f, ii = 0.f;
#pragma unroll
        for (int i = 0; i < W; i++) {
            float wwr = wr[i * W + o], wwi = wi[i * W + o];
            rr += ar[i] * wwr - ai[i] * wwi;
            ii += ar[i] * wwi + ai[i] * wwr;
        }
        if (corner) {
            rr += ere[ebase + o * NMODE];
            ii += eim[ebase + o * NMODE];
        }
        rr *= sm;
        ii *= sm;
        rr = s27_gelu(rr);
        ii = s27_gelu(ii);
        xre[(size_t)(b * W + o) * XYZ + p] = rr;
        xim[(size_t)(b * W + o) * XYZ + p] = ii;
        if (corner) {
            xcRe[(size_t)(b * W + o) * 2048 + cidx] = rr;
            xcIm[(size_t)(b * W + o) * 2048 + cidx] = ii;
        }
    }
}

// TAIL v2: 2 grid points per thread; all weights via wave-uniform s_load;
// zero LDS. Points p and p+1 share b (XYZ even, flat index even).
__global__ __launch_bounds__(256, 2)
void s27_tail(const float* __restrict__ xre, const float* __restrict__ xim,
              const float* __restrict__ ere, const float* __restrict__ eim,
              const float* __restrict__ wpt_r, const float* __restrict__ wpt_i,
              const float* __restrict__ smooth,
              const float* __restrict__ f1r, const float* __restrict__ f1i,
              const float* __restrict__ f2r, const float* __restrict__ f2i,
              float* __restrict__ outf) {
    const float* pwr = wpt_r + 3 * W * W;
    const float* pwi = wpt_i + 3 * W * W;
    int idx = blockIdx.x * blockDim.x + threadIdx.x;
    size_t f = (size_t)idx * 2;
    if (f >= (size_t)4 * XYZ) return;
    int b = (int)(f / XYZ);
    int p0 = (int)(f % XYZ);          // even; p1 = p0+1 in same b

    // corner info per point
    int gz0 = p0 % 33, gxy0 = p0 / 33;
    int gy0 = gxy0 & 63, gx0 = gxy0 >> 6;
    int kx0 = (gx0 < 8) ? gx0 : ((gx0 >= 56) ? gx0 - 48 : -1);
    int ky0 = (gy0 < 8) ? gy0 : ((gy0 >= 56) ? gy0 - 48 : -1);
    bool c0 = (kx0 >= 0) && (ky0 >= 0) && (gz0 < 8);
    int eb0 = c0 ? (b * W * NMODE + (kx0 * 16 + ky0) * 8 + gz0) : 0;
    int p1 = p0 + 1;
    int gz1 = p1 % 33, gxy1 = p1 / 33;
    int gy1 = gxy1 & 63, gx1 = gxy1 >> 6;
    int kx1 = (gx1 < 8) ? gx1 : ((gx1 >= 56) ? gx1 - 48 : -1);
    int ky1 = (gy1 < 8) ? gy1 : ((gy1 >= 56) ? gy1 - 48 : -1);
    bool c1 = (kx1 >= 0) && (ky1 >= 0) && (gz1 < 8);
    int eb1 = c1 ? (b * W * NMODE + (kx1 * 16 + ky1) * 8 + gz1) : 0;
    float2 smv = *(const float2*)&smooth[p0];

    // fused combine l=3 (no gelu) for both points
    float r0_[W], i0_[W], r1_[W], i1_[W];
    {
        float a0r[W], a0i[W], a1r[W], a1i[W];
#pragma unroll
        for (int i = 0; i < W; i++) {
            float2 vr = *(const float2*)&xre[(size_t)(b * W + i) * XYZ + p0];
            float2 vi = *(const float2*)&xim[(size_t)(b * W + i) * XYZ + p0];
            a0r[i] = vr.x; a1r[i] = vr.y;
            a0i[i] = vi.x; a1i[i] = vi.y;
        }
#pragma unroll 1
        for (int o = 0; o < W; o++) {
            float rr0 = 0.f, ii0 = 0.f, rr1 = 0.f, ii1 = 0.f;
#pragma unroll
            for (int i = 0; i < W; i++) {
                float wwr = pwr[i * W + o], wwi = pwi[i * W + o];
                rr0 += a0r[i] * wwr - a0i[i] * wwi;
                ii0 += a0r[i] * wwi + a0i[i] * wwr;
                rr1 += a1r[i] * wwr - a1i[i] * wwi;
                ii1 += a1r[i] * wwi + a1i[i] * wwr;
            }
            if (c0) { rr0 += ere[eb0 + o * NMODE]; ii0 += eim[eb0 + o * NMODE]; }
            if (c1) { rr1 += ere[eb1 + o * NMODE]; ii1 += eim[eb1 + o * NMODE]; }
            r0_[o] = rr0 * smv.x;  i0_[o] = ii0 * smv.x;
            r1_[o] = rr1 * smv.y;  i1_[o] = ii1 * smv.y;
        }
    }
    // fc1 -> cgelu -> fc2 (real out), both points sharing weight s_loads
    float acc0[3] = {0.f, 0.f, 0.f}, acc1[3] = {0.f, 0.f, 0.f};
    for (int jc = 0; jc < 16; jc++) {
        int jb = jc * 8;
        float t0r[8], t0i[8], t1r[8], t1i[8];
#pragma unroll
        for (int jj = 0; jj < 8; jj++) { t0r[jj] = 0.f; t0i[jj] = 0.f; t1r[jj] = 0.f; t1i[jj] = 0.f; }
#pragma unroll 1
        for (int i = 0; i < W; i++) {
            float4 wrA = *(const float4*)&f1r[i * 128 + jb];
            float4 wrB = *(const float4*)&f1r[i * 128 + jb + 4];
            float4 wiA = *(const float4*)&f1i[i * 128 + jb];
            float4 wiB = *(const float4*)&f1i[i * 128 + jb + 4];
            float x0r = r0_[i], x0i = i0_[i], x1r = r1_[i], x1i = i1_[i];
            t0r[0] += x0r * wrA.x - x0i * wiA.x;  t0i[0] += x0r * wiA.x + x0i * wrA.x;
            t1r[0] += x1r * wrA.x - x1i * wiA.x;  t1i[0] += x1r * wiA.x + x1i * wrA.x;
            t0r[1] += x0r * wrA.y - x0i * wiA.y;  t0i[1] += x0r * wiA.y + x0i * wrA.y;
            t1r[1] += x1r * wrA.y - x1i * wiA.y;  t1i[1] += x1r * wiA.y + x1i * wrA.y;
            t0r[2] += x0r * wrA.z - x0i * wiA.z;  t0i[2] += x0r * wiA.z + x0i * wrA.z;
            t1r[2] += x1r * wrA.z - x1i * wiA.z;  t1i[2] += x1r * wiA.z + x1i * wrA.z;
            t0r[3] += x0r * wrA.w - x0i * wiA.w;  t0i[3] += x0r * wiA.w + x0i * wrA.w;
            t1r[3] += x1r * wrA.w - x1i * wiA.w;  t1i[3] += x1r * wiA.w + x1i * wrA.w;
            t0r[4] += x0r * wrB.x - x0i * wiB.x;  t0i[4] += x0r * wiB.x + x0i * wrB.x;
            t1r[4] += x1r * wrB.x - x1i * wiB.x;  t1i[4] += x1r * wiB.x + x1i * wrB.x;
            t0r[5] += x0r * wrB.y - x0i * wiB.y;  t0i[5] += x0r * wiB.y + x0i * wrB.y;
            t1r[5] += x1r * wrB.y - x1i * wiB.y;  t1i[5] += x1r * wiB.y + x1i * wrB.y;
            t0r[6] += x0r * wrB.z - x0i * wiB.z;  t0i[6] += x0r * wiB.z + x0i * wrB.z;
            t1r[6] += x1r * wrB.z - x1i * wiB.z;  t1i[6] += x1r * wiB.z + x1i * wrB.z;
            t0r[7] += x0r * wrB.w - x0i * wiB.w;  t0i[7] += x0r * wiB.w + x0i * wrB.w;
            t1r[7] += x1r * wrB.w - x1i * wiB.w;  t1i[7] += x1r * wiB.w + x1i * wrB.w;
        }
#pragma unroll
        for (int jj = 0; jj < 8; jj++) {
            t0r[jj] = s27_gelu(t0r[jj]);
            t0i[jj] = s27_gelu(t0i[jj]);
            t1r[jj] = s27_gelu(t1r[jj]);
            t1i[jj] = s27_gelu(t1i[jj]);
        }
#pragma unroll
        for (int jj = 0; jj < 8; jj++) {
            int j = jb + jj;
#pragma unroll
            for (int o = 0; o < 3; o++) {
                float cr = f2r[j * 3 + o], ci = f2i[j * 3 + o];   // uniform -> s_load
                acc0[o] += t0r[jj] * cr - t0i[jj] * ci;
                acc1[o] += t1r[jj] * cr - t1i[jj] * ci;
            }
        }
    }
#pragma unroll
    for (int o = 0; o < 3; o++) {
        size_t k = (size_t)(b * 3 + o) * XYZ + p0;
        float2 out2;
        out2.x = __bfloat162float(__float2bfloat16(acc0[o]));
        out2.y = __bfloat162float(__float2bfloat16(acc1[o]));
        *(float2*)&outf[k] = out2;
    }
}

extern "C" void kernel_launch(void* const* d_in, const int* in_sizes, int n_in,
                              void* d_out, int out_size, void* d_ws, size_t ws_size,
                              hipStream_t stream) {
    const float* x_r    = (const float*)d_in[0];
    const float* x_i    = (const float*)d_in[1];
    const float* smooth = (const float*)d_in[2];
    const float* wconv  = (const float*)d_in[3];
    const float* wpt_r  = (const float*)d_in[4];
    const float* wpt_i  = (const float*)d_in[5];
    const float* fc0_r  = (const float*)d_in[6];
    const float* fc0_i  = (const float*)d_in[7];
    const float* fc1_r  = (const float*)d_in[8];
    const float* fc1_i  = (const float*)d_in[9];
    const float* fc2_r  = (const float*)d_in[10];
    const float* fc2_i  = (const float*)d_in[11];
    float* outf = (float*)d_out;

    const size_t NBW = (size_t)4 * W * XYZ;
    const size_t NM  = (size_t)80 * NMODE;

    float* ws   = (float*)d_ws;
    float* eRe  = ws;
    float* eIm  = eRe + NM;
    float* tRe  = eIm + NM;
    float* tIm  = tRe + NM;
    float* xcRe = tIm + NM;
    float* xcIm = xcRe + NM;
    float* xre  = xcIm + NM;
    float* xim  = xre + NBW;

    dim3 blk(256);
    const int gP = (4 * XYZ) / 256;        // 2112
    const int gT = (2 * XYZ) / 256;        // 1056 (2 pts/thread)

    s27_fc0<<<gP, blk, 0, stream>>>(x_r, x_i, fc0_r, fc0_i, xre, xim, xcRe, xcIm);
    for (int l = 0; l < 4; l++) {
        s27_ixy<<<640, blk, 0, stream>>>(xcRe, xcIm, tRe, tIm);
        s27_zchain<<<256, blk, 0, stream>>>(tRe, tIm, wconv, l, eRe, eIm);
        s27_fxy<<<640, blk, 0, stream>>>(eRe, eIm, tRe, tIm);
        if (l < 3)
            s27_combine<<<gP, blk, 0, stream>>>(xre, xim, tRe, tIm,
                                                wpt_r, wpt_i, l, smooth,
                                                xcRe, xcIm);
    }
    s27_tail<<<gT, blk, 0, stream>>>(xre, xim, tRe, tIm, wpt_r, wpt_i, smooth,
                                     fc1_r, fc1_i, fc2_r, fc2_i, outf);
}

// Round 28
// 643.288 us; speedup vs baseline: 1.3019x; 1.3019x over previous
//
#include <hip/hip_runtime.h>
#include <hip/hip_bf16.h>
#include <math.h>

// build t28 = r26 verbatim (best verified: 647 us), fresh symbols.
// r26 = fused spectral chains (ixy/zchain/fxy) + coalesced corner mirror xc +
// s_load weights + tail(minwaves2, fused combine l=3).
#define XYZ 135168   // 64*64*33
#define W 20
#define NMODE 2048   // 16*16*8
#define NREAL 3584   // 16*16*14

__device__ __forceinline__ float t28_erf(float x) {
    float s = (x < 0.f) ? -1.f : 1.f;
    float a = fabsf(x);
    float t = 1.f / fmaf(0.3275911f, a, 1.f);
    float poly = t * fmaf(t, fmaf(t, fmaf(t, fmaf(t, 1.061405429f, -1.453152027f),
                                           1.421413741f), -0.284496736f), 0.254829592f);
    float e = __expf(-a * a);
    return s * (1.f - poly * e);
}
__device__ __forceinline__ float t28_gelu(float v) {
    return 0.5f * v * (1.0f + t28_erf(v * 0.7071067811865476f));
}

__global__ __launch_bounds__(256, 4)
void t28_fc0(const float* __restrict__ xr_in, const float* __restrict__ xi_in,
             const float* __restrict__ fr, const float* __restrict__ fi,
             float* __restrict__ xre, float* __restrict__ xim,
             float* __restrict__ xcRe, float* __restrict__ xcIm) {
    int idx = blockIdx.x * blockDim.x + threadIdx.x;
    if (idx >= 4 * XYZ) return;
    int b = idx / XYZ, p = idx % XYZ;
    int gz = p % 33;
    int gxy = p / 33;
    int gy = gxy & 63;
    int gx = gxy >> 6;
    int kx = (gx < 8) ? gx : ((gx >= 56) ? gx - 48 : -1);
    int ky = (gy < 8) ? gy : ((gy >= 56) ? gy - 48 : -1);
    bool corner = (kx >= 0) && (ky >= 0) && (gz < 8);
    int cidx = corner ? (gz * 256 + kx * 16 + ky) : 0;
    float ar[3], ai[3];
#pragma unroll
    for (int i = 0; i < 3; i++) {
        ar[i] = xr_in[(size_t)(b * 3 + i) * XYZ + p];
        ai[i] = xi_in[(size_t)(b * 3 + i) * XYZ + p];
    }
#pragma unroll
    for (int o = 0; o < W; o++) {
        float rr = 0.f, ii = 0.f;
#pragma unroll
        for (int i = 0; i < 3; i++) {
            float wr = fr[i * W + o], wi = fi[i * W + o];
            rr += ar[i] * wr - ai[i] * wi;
            ii += ar[i] * wi + ai[i] * wr;
        }
        xre[(size_t)(b * W + o) * XYZ + p] = rr;
        xim[(size_t)(b * W + o) * XYZ + p] = ii;
        if (corner) {
            xcRe[(size_t)(b * W + o) * 2048 + cidx] = rr;
            xcIm[(size_t)(b * W + o) * 2048 + cidx] = ii;
        }
    }
}

__global__ __launch_bounds__(256, 4)
void t28_ixy(const float* __restrict__ xcRe, const float* __restrict__ xcIm,
             float* __restrict__ aRe, float* __restrict__ aIm) {
    __shared__ float s0r[256], s0i[256], s1r[256], s1i[256];
    __shared__ float twc[16], tws[16];
    int bc = blockIdx.x >> 3;
    int kz = blockIdx.x & 7;
    int t = threadIdx.x;
    int hi = t >> 4, lo = t & 15;
    if (t < 16) {
        float s, c;
        sincosf((float)t * 0.39269908169872414f, &s, &c);
        twc[t] = c; tws[t] = s;
    }
    {
        size_t g = (size_t)bc * 2048 + (size_t)kz * 256 + t;
        s0r[t] = xcRe[g];
        s0i[t] = xcIm[g];
    }
    __syncthreads();
    {
        int nx = hi, ky = lo;
        float accr = 0.f, acci = 0.f;
        for (int kx = 0; kx < 16; kx++) {
            float vr = s0r[kx * 16 + ky], vi = s0i[kx * 16 + ky];
            int m = (kx * nx) & 15;
            float c = twc[m], s = tws[m];
            accr += vr * c - vi * s;
            acci += vr * s + vi * c;
        }
        s1r[t] = accr * 0.0625f;
        s1i[t] = acci * 0.0625f;
    }
    __syncthreads();
    {
        int nx = hi, ny = lo;
        float accr = 0.f, acci = 0.f;
        for (int ky = 0; ky < 16; ky++) {
            float vr = s1r[nx * 16 + ky], vi = s1i[nx * 16 + ky];
            int m = (ky * ny) & 15;
            float c = twc[m], s = tws[m];
            accr += vr * c - vi * s;
            acci += vr * s + vi * c;
        }
        size_t o = (size_t)bc * 2048 + (size_t)t * 8 + kz;
        aRe[o] = accr * 0.0625f;
        aIm[o] = acci * 0.0625f;
    }
}

__global__ __launch_bounds__(256, 4)
void t28_zchain(const float* __restrict__ aRe, const float* __restrict__ aIm,
                const float* __restrict__ wconv, int l,
                float* __restrict__ tRe, float* __restrict__ tIm) {
    __shared__ float sar[640], sai[640];
    __shared__ float sr1[1120], sr2[1120];
    __shared__ float twc[14], tws[14];
    int b = blockIdx.x >> 6;
    int q0 = (blockIdx.x & 63) * 4;
    int tid = threadIdx.x;
    if (tid < 14) {
        float s, c;
        sincosf((float)tid * 0.4487989505128276f, &s, &c);
        twc[tid] = c; tws[tid] = s;
    }
    for (int t = tid; t < 640; t += 256) {
        int c = t >> 5;
        int dq = (t >> 3) & 3;
        int k = t & 7;
        size_t g = (size_t)(b * 20 + c) * 2048 + (size_t)(q0 + dq) * 8 + k;
        sar[t] = aRe[g];
        sai[t] = aIm[g];
    }
    __syncthreads();
    for (int t = tid; t < 1120; t += 256) {
        int c = t / 56;
        int rem = t % 56;
        int dq = rem / 14, nz = rem % 14;
        int base = c * 32 + dq * 8;
        float acc = sar[base];
        float re7 = sar[base + 7];
        acc += (nz & 1) ? -re7 : re7;
        for (int k = 1; k < 7; k++) {
            int m = (k * nz) % 14;
            acc += 2.f * (sar[base + k] * twc[m] - sai[base + k] * tws[m]);
        }
        sr1[t] = acc * (1.0f / 14.0f);
    }
    __syncthreads();
    {
        const float* wl = wconv + (size_t)l * W * W * NREAL;
        for (int t = tid; t < 1120; t += 256) {
            int o = t / 56;
            int rem = t % 56;
            int dq = rem / 14, nz = rem % 14;
            int p = (q0 + dq) * 14 + nz;
            float acc = 0.f;
#pragma unroll 4
            for (int i = 0; i < W; i++)
                acc += sr1[i * 56 + rem] * wl[(size_t)(i * W + o) * NREAL + p];
            sr2[t] = acc;
        }
    }
    __syncthreads();
    for (int t = tid; t < 640; t += 256) {
        int c = t >> 5;
        int dq = (t >> 3) & 3;
        int k = t & 7;
        int base = c * 56 + dq * 14;
        float accr = 0.f, acci = 0.f;
        for (int n = 0; n < 14; n++) {
            float v = sr2[base + n];
            int m = (k * n) % 14;
            accr += v * twc[m];
            acci -= v * tws[m];
        }
        size_t g = (size_t)(b * 20 + c) * 2048 + (size_t)(q0 + dq) * 8 + k;
        tRe[g] = accr;
        tIm[g] = acci;
    }
}

__global__ __launch_bounds__(256, 4)
void t28_fxy(const float* __restrict__ c1Re, const float* __restrict__ c1Im,
             float* __restrict__ eRe, float* __restrict__ eIm) {
    __shared__ float s0r[256], s0i[256], s1r[256], s1i[256];
    __shared__ float twc[16], tws[16];
    int bc = blockIdx.x >> 3;
    int kz = blockIdx.x & 7;
    int t = threadIdx.x;
    int hi = t >> 4, lo = t & 15;
    if (t < 16) {
        float s, c;
        sincosf((float)t * 0.39269908169872414f, &s, &c);
        twc[t] = c; tws[t] = s;
    }
    {
        size_t o = (size_t)bc * 2048 + (size_t)t * 8 + kz;
        s0r[t] = c1Re[o];
        s0i[t] = c1Im[o];
    }
    __syncthreads();
    {
        int kx = hi, ny = lo;
        float accr = 0.f, acci = 0.f;
        for (int nx = 0; nx < 16; nx++) {
            float vr = s0r[nx * 16 + ny], vi = s0i[nx * 16 + ny];
            int m = (kx * nx) & 15;
            float c = twc[m], s = tws[m];
            accr += vr * c + vi * s;
            acci += vi * c - vr * s;
        }
        s1r[t] = accr;
        s1i[t] = acci;
    }
    __syncthreads();
    {
        int kx = hi, ky = lo;
        float accr = 0.f, acci = 0.f;
        for (int ny = 0; ny < 16; ny++) {
            float vr = s1r[kx * 16 + ny], vi = s1i[kx * 16 + ny];
            int m = (ky * ny) & 15;
            float c = twc[m], s = tws[m];
            accr += vr * c + vi * s;
            acci += vi * c - vr * s;
        }
        size_t o = (size_t)bc * 2048 + (size_t)t * 8 + kz;
        eRe[o] = accr;
        eIm[o] = acci;
    }
}

__global__ __launch_bounds__(256, 4)
void t28_combine(float* __restrict__ xre, float* __restrict__ xim,
                 const float* __restrict__ ere, const float* __restrict__ eim,
                 const float* __restrict__ wpt_r, const float* __restrict__ wpt_i,
                 int l, const float* __restrict__ smooth,
                 float* __restrict__ xcRe, float* __restrict__ xcIm) {
    const float* wr = wpt_r + l * W * W;
    const float* wi = wpt_i + l * W * W;
    int idx = blockIdx.x * blockDim.x + threadIdx.x;
    if (idx >= 4 * XYZ) return;
    int b = idx / XYZ, p = idx % XYZ;
    int gz = p % 33;
    int gxy = p / 33;
    int gy = gxy & 63;
    int gx = gxy >> 6;
    int kx = (gx < 8) ? gx : ((gx >= 56) ? gx - 48 : -1);
    int ky = (gy < 8) ? gy : ((gy >= 56) ? gy - 48 : -1);
    bool corner = (kx >= 0) && (ky >= 0) && (gz < 8);
    int cidx = corner ? (gz * 256 + kx * 16 + ky) : 0;
    float sm = smooth[p];
    float ar[W], ai[W];
#pragma unroll
    for (int i = 0; i < W; i++) {
        ar[i] = xre[(size_t)(b * W + i) * XYZ + p];
        ai[i] = xim[(size_t)(b * W + i) * XYZ + p];
    }
    int ebase = corner ? (b * W * NMODE + (kx * 16 + ky) * 8 + gz) : 0;
    for (int o = 0; o < W; o++) {
        float rr = 0.f, ii = 0.f;
#pragma unroll
        for (int i = 0; i < W; i++) {
            float wwr = wr[i * W + o], wwi = wi[i * W + o];
            rr += ar[i] * wwr - ai[i] * wwi;
            ii += ar[i] * wwi + ai[i] * wwr;
        }
        if (corner) {
            rr += ere[ebase + o * NMODE];
            ii += eim[ebase + o * NMODE];
        }
        rr *= sm;
        ii *= sm;
        rr = t28_gelu(rr);
        ii = t28_gelu(ii);
        xre[(size_t)(b * W + o) * XYZ + p] = rr;
        xim[(size_t)(b * W + o) * XYZ + p] = ii;
        if (corner) {
            xcRe[(size_t)(b * W + o) * 2048 + cidx] = rr;
            xcIm[(size_t)(b * W + o) * 2048 + cidx] = ii;
        }
    }
}

__global__ __launch_bounds__(256, 2)
void t28_tail(const float* __restrict__ xre, const float* __restrict__ xim,
              const float* __restrict__ ere, const float* __restrict__ eim,
              const float* __restrict__ wpt_r, const float* __restrict__ wpt_i,
              const float* __restrict__ smooth,
              const float* __restrict__ f1r, const float* __restrict__ f1i,
              const float* __restrict__ f2r, const float* __restrict__ f2i,
              float* __restrict__ outf) {
    __shared__ __align__(16) float w2r[3 * 128], w2i[3 * 128];
    for (int i = threadIdx.x; i < 3 * 128; i += blockDim.x) {
        int j = i & 127, o = i >> 7;
        w2r[o * 128 + j] = f2r[j * 3 + o];
        w2i[o * 128 + j] = f2i[j * 3 + o];
    }
    const float* pwr = wpt_r + 3 * W * W;
    const float* pwi = wpt_i + 3 * W * W;
    __syncthreads();
    int idx = blockIdx.x * blockDim.x + threadIdx.x;
    if (idx >= 4 * XYZ) return;
    int b = idx / XYZ, p = idx % XYZ;
    int gz = p % 33;
    int gxy = p / 33;
    int gy = gxy & 63;
    int gx = gxy >> 6;
    int kxc = (gx < 8) ? gx : ((gx >= 56) ? gx - 48 : -1);
    int kyc = (gy < 8) ? gy : ((gy >= 56) ? gy - 48 : -1);
    bool corner = (kxc >= 0) && (kyc >= 0) && (gz < 8);
    float sm = smooth[p];
    float rr_[W], ri_[W];
    {
        float ar[W], ai[W];
#pragma unroll
        for (int i = 0; i < W; i++) {
            ar[i] = xre[(size_t)(b * W + i) * XYZ + p];
            ai[i] = xim[(size_t)(b * W + i) * XYZ + p];
        }
        int ebase = corner ? (b * W * NMODE + (kxc * 16 + kyc) * 8 + gz) : 0;
#pragma unroll 1
        for (int o = 0; o < W; o++) {
            float rr = 0.f, ii = 0.f;
#pragma unroll
            for (int i = 0; i < W; i++) {
                float wwr = pwr[i * W + o], wwi = pwi[i * W + o];
                rr += ar[i] * wwr - ai[i] * wwi;
                ii += ar[i] * wwi + ai[i] * wwr;
            }
            if (corner) {
                rr += ere[ebase + o * NMODE];
                ii += eim[ebase + o * NMODE];
            }
            rr_[o] = rr * sm;
            ri_[o] = ii * sm;
        }
    }
    float accr[3] = {0.f, 0.f, 0.f};
    for (int jc = 0; jc < 16; jc++) {
        int jb = jc * 8;
        float tr[8], ti[8];
#pragma unroll
        for (int jj = 0; jj < 8; jj++) { tr[jj] = 0.f; ti[jj] = 0.f; }
#pragma unroll 2
        for (int i = 0; i < W; i++) {
            float4 wrA = *(const float4*)&f1r[i * 128 + jb];
            float4 wrB = *(const float4*)&f1r[i * 128 + jb + 4];
            float4 wiA = *(const float4*)&f1i[i * 128 + jb];
            float4 wiB = *(const float4*)&f1i[i * 128 + jb + 4];
            float xr_ = rr_[i], xi_ = ri_[i];
            tr[0] += xr_ * wrA.x - xi_ * wiA.x;  ti[0] += xr_ * wiA.x + xi_ * wrA.x;
            tr[1] += xr_ * wrA.y - xi_ * wiA.y;  ti[1] += xr_ * wiA.y + xi_ * wrA.y;
            tr[2] += xr_ * wrA.z - xi_ * wiA.z;  ti[2] += xr_ * wiA.z + xi_ * wrA.z;
            tr[3] += xr_ * wrA.w - xi_ * wiA.w;  ti[3] += xr_ * wiA.w + xi_ * wrA.w;
            tr[4] += xr_ * wrB.x - xi_ * wiB.x;  ti[4] += xr_ * wiB.x + xi_ * wrB.x;
            tr[5] += xr_ * wrB.y - xi_ * wiB.y;  ti[5] += xr_ * wiB.y + xi_ * wrB.y;
            tr[6] += xr_ * wrB.z - xi_ * wiB.z;  ti[6] += xr_ * wiB.z + xi_ * wrB.z;
            tr[7] += xr_ * wrB.w - xi_ * wiB.w;  ti[7] += xr_ * wiB.w + xi_ * wrB.w;
        }
#pragma unroll
        for (int jj = 0; jj < 8; jj++) {
            tr[jj] = t28_gelu(tr[jj]);
            ti[jj] = t28_gelu(ti[jj]);
        }
#pragma unroll
        for (int o = 0; o < 3; o++) {
            float4 crA = *(const float4*)&w2r[o * 128 + jb];
            float4 crB = *(const float4*)&w2r[o * 128 + jb + 4];
            float4 ciA = *(const float4*)&w2i[o * 128 + jb];
            float4 ciB = *(const float4*)&w2i[o * 128 + jb + 4];
            accr[o] += tr[0] * crA.x - ti[0] * ciA.x;
            accr[o] += tr[1] * crA.y - ti[1] * ciA.y;
            accr[o] += tr[2] * crA.z - ti[2] * ciA.z;
            accr[o] += tr[3] * crA.w - ti[3] * ciA.w;
            accr[o] += tr[4] * crB.x - ti[4] * ciB.x;
            accr[o] += tr[5] * crB.y - ti[5] * ciB.y;
            accr[o] += tr[6] * crB.z - ti[6] * ciB.z;
            accr[o] += tr[7] * crB.w - ti[7] * ciB.w;
        }
    }
#pragma unroll
    for (int o = 0; o < 3; o++) {
        size_t k = (size_t)(b * 3 + o) * XYZ + p;
        outf[k] = __bfloat162float(__float2bfloat16(accr[o]));
    }
}

extern "C" void kernel_launch(void* const* d_in, const int* in_sizes, int n_in,
                              void* d_out, int out_size, void* d_ws, size_t ws_size,
                              hipStream_t stream) {
    const float* x_r    = (const float*)d_in[0];
    const float* x_i    = (const float*)d_in[1];
    const float* smooth = (const float*)d_in[2];
    const float* wconv  = (const float*)d_in[3];
    const float* wpt_r  = (const float*)d_in[4];
    const float* wpt_i  = (const float*)d_in[5];
    const float* fc0_r  = (const float*)d_in[6];
    const float* fc0_i  = (const float*)d_in[7];
    const float* fc1_r  = (const float*)d_in[8];
    const float* fc1_i  = (const float*)d_in[9];
    const float* fc2_r  = (const float*)d_in[10];
    const float* fc2_i  = (const float*)d_in[11];
    float* outf = (float*)d_out;

    const size_t NBW = (size_t)4 * W * XYZ;
    const size_t NM  = (size_t)80 * NMODE;

    float* ws   = (float*)d_ws;
    float* eRe  = ws;
    float* eIm  = eRe + NM;
    float* tRe  = eIm + NM;
    float* tIm  = tRe + NM;
    float* xcRe = tIm + NM;
    float* xcIm = xcRe + NM;
    float* xre  = xcIm + NM;
    float* xim  = xre + NBW;

    dim3 blk(256);
    const int gP = (4 * XYZ) / 256;

    t28_fc0<<<gP, blk, 0, stream>>>(x_r, x_i, fc0_r, fc0_i, xre, xim, xcRe, xcIm);
    for (int l = 0; l < 4; l++) {
        t28_ixy<<<640, blk, 0, stream>>>(xcRe, xcIm, tRe, tIm);
        t28_zchain<<<256, blk, 0, stream>>>(tRe, tIm, wconv, l, eRe, eIm);
        t28_fxy<<<640, blk, 0, stream>>>(eRe, eIm, tRe, tIm);
        if (l < 3)
            t28_combine<<<gP, blk, 0, stream>>>(xre, xim, tRe, tIm,
                                                wpt_r, wpt_i, l, smooth,
                                                xcRe, xcIm);
    }
    t28_tail<<<gP, blk, 0, stream>>>(xre, xim, tRe, tIm, wpt_r, wpt_i, smooth,
                                     fc1_r, fc1_i, fc2_r, fc2_i, outf);
}